// Round 9
// baseline (1133.784 us; speedup 1.0000x reference)
//
#include <hip/hip_runtime.h>

#define NN 100000
#define CC 128
#define EE 1600000
#define GG 1024
#define LL 5
#define NBUCKET 12500        // NN/8; 8 nodes per bucket

typedef __attribute__((ext_vector_type(8))) short bf16x8;
typedef __attribute__((ext_vector_type(4))) float f32x4;

__device__ __forceinline__ float sigmoidf_(float x) { return 1.0f / (1.0f + __expf(-x)); }
__device__ __forceinline__ float tanhf_(float x) {
  float xx = fminf(15.0f, fmaxf(-15.0f, x));
  float t = __expf(-2.0f * xx);
  return (1.0f - t) / (1.0f + t);
}
__device__ __forceinline__ unsigned short f2bf(float x) {
  unsigned int u = __float_as_uint(x);
  return (unsigned short)((u + 0x7fffu + ((u >> 16) & 1u)) >> 16);
}
__device__ __forceinline__ float bflo(unsigned int u) { return __uint_as_float(u << 16); }
__device__ __forceinline__ float bfhi(unsigned int u) { return __uint_as_float(u & 0xffff0000u); }
__device__ __forceinline__ float bf2f(unsigned short v) { return __uint_as_float((unsigned)v << 16); }

// ---------------- weight prepack ----------------
// Packed B-fragment layout: element (k, c) at t = ((cb*4+ks)*64 + l)*8 + i
// with k = ks*32 + 8*(l>>4) + i, c = cb*16 + (l&15).

__global__ __launch_bounds__(256) void pack_kernel(
    const float* __restrict__ src, unsigned short* __restrict__ dst)
{
  int t = blockIdx.x * 256 + threadIdx.x;           // 49152
  int i = t & 7, l = (t >> 3) & 63, q = t >> 9;
  int ks = q & 3, cb = q >> 2;
  int k = ks * 32 + 8 * (l >> 4) + i;
  int c = cb * 16 + (l & 15);
  dst[t] = f2bf(src[(size_t)c * CC + k]);
}

// Wfuse_l[k][c] = sum_j W_l[k][j] * W_ih[c][j]
__global__ __launch_bounds__(256) void fuse_pack_kernel(
    const float* __restrict__ Wl, const float* __restrict__ W_ih,
    unsigned short* __restrict__ dst)
{
  int t = blockIdx.x * 256 + threadIdx.x;           // 49152 per layer
  int i = t & 7, l = (t >> 3) & 63, q = t >> 9;
  int ks = q & 3, cb = q >> 2;
  int k = ks * 32 + 8 * (l >> 4) + i;
  int c = cb * 16 + (l & 15);
  const float* wl = Wl + (size_t)k * CC;
  const float* wi = W_ih + (size_t)c * CC;
  float acc = 0.f;
  #pragma unroll 8
  for (int j = 0; j < CC; ++j) acc = fmaf(wl[j], wi[j], acc);
  dst[t] = f2bf(acc);
}

// ---------------- CSR build (once per call) ----------------

__global__ __launch_bounds__(256) void hist_kernel(const int* __restrict__ eidx,
                                                   int* __restrict__ deg)
{
  int e = blockIdx.x * blockDim.x + threadIdx.x;
  if (e < EE) atomicAdd(&deg[eidx[EE + e]], 1);
}

__global__ __launch_bounds__(256) void scan1_kernel(const int* __restrict__ deg,
                                                    int* __restrict__ bsum)
{
  __shared__ int red[4];
  int base = blockIdx.x * 1024 + threadIdx.x * 4;
  int s = 0;
  #pragma unroll
  for (int i = 0; i < 4; ++i) { int idx = base + i; if (idx < NN) s += deg[idx]; }
  #pragma unroll
  for (int off = 32; off; off >>= 1) s += __shfl_down(s, off, 64);
  if ((threadIdx.x & 63) == 0) red[threadIdx.x >> 6] = s;
  __syncthreads();
  if (threadIdx.x == 0) bsum[blockIdx.x] = red[0] + red[1] + red[2] + red[3];
}

__global__ void scan2_kernel(int* __restrict__ bsum, int nb)
{
  if (threadIdx.x == 0 && blockIdx.x == 0) {
    int acc = 0;
    for (int i = 0; i < nb; ++i) { int v = bsum[i]; bsum[i] = acc; acc += v; }
  }
}

__global__ __launch_bounds__(256) void scan3_kernel(const int* __restrict__ deg,
                                                    const int* __restrict__ bsum,
                                                    int* __restrict__ row_ptr)
{
  __shared__ int ts[256];
  const int tid = threadIdx.x;
  const int base = blockIdx.x * 1024 + tid * 4;
  int v[4]; int s = 0;
  #pragma unroll
  for (int i = 0; i < 4; ++i) { int idx = base + i; v[i] = (idx < NN) ? deg[idx] : 0; s += v[i]; }
  ts[tid] = s; __syncthreads();
  for (int off = 1; off < 256; off <<= 1) {
    int t = (tid >= off) ? ts[tid - off] : 0;
    __syncthreads();
    ts[tid] += t;
    __syncthreads();
  }
  int excl = bsum[blockIdx.x] + ts[tid] - s;
  #pragma unroll
  for (int i = 0; i < 4; ++i) {
    int idx = base + i;
    if (idx < NN) { row_ptr[idx] = excl; excl += v[i]; }
  }
  if (blockIdx.x == 0 && tid == 0) row_ptr[NN] = EE;
}

__global__ void bcur_init_kernel(const int* __restrict__ row_ptr, int* __restrict__ bcur)
{
  int b = blockIdx.x * blockDim.x + threadIdx.x;
  if (b < NBUCKET) bcur[b] = row_ptr[b * 8];
}

// phase 1: append edges into dst-bucket span (12500 cursors, low contention)
__global__ __launch_bounds__(256) void fill_bucket_kernel(
    const int* __restrict__ eidx, const float* __restrict__ ew,
    int* __restrict__ bcur, int2* __restrict__ bucket)
{
  int e = blockIdx.x * blockDim.x + threadIdx.x;
  if (e < EE) {
    int d = eidx[EE + e];
    int p = atomicAdd(&bcur[d >> 3], 1);
    bucket[p] = make_int2(eidx[e] | ((d & 7) << 17), __float_as_int(ew[e]));
  }
}

// phase 2: one block per bucket; 8 LDS cursors; scatter within ~1KB L2 span
__global__ __launch_bounds__(128) void fill_csr_kernel(
    const int* __restrict__ row_ptr, const int2* __restrict__ bucket,
    int2* __restrict__ csr_sw)
{
  __shared__ int cur[8];
  const int b = blockIdx.x;
  const int tid = threadIdx.x;
  if (tid < 8) cur[tid] = row_ptr[b * 8 + tid];
  __syncthreads();
  const int start = row_ptr[b * 8];
  const int stop  = row_ptr[b * 8 + 8];
  for (int j = start + tid; j < stop; j += 128) {
    int2 r = bucket[j];
    unsigned u = (unsigned)r.x;
    int p = atomicAdd(&cur[u >> 17], 1);
    csr_sw[p] = make_int2((int)(u & 0x1FFFFu), r.y);
  }
}

// ---------------- main pipeline ----------------

// h0 = x @ W_emb + b_emb; bf16 state
__global__ __launch_bounds__(128) void embed_kernel(
    const float* __restrict__ x, const float* __restrict__ W_emb,
    const float* __restrict__ b_emb, unsigned short* __restrict__ h_bf)
{
  const int node = blockIdx.x;
  const int c = threadIdx.x;
  float acc = b_emb[c];
  #pragma unroll
  for (int k = 0; k < 32; ++k)
    acc = fmaf(x[node * 32 + k], W_emb[k * CC + c], acc);
  h_bf[(size_t)node * CC + c] = f2bf(acc);
}

// Fused layer: per wave, (1) CSR-gather 32 nodes' agg into LDS (bf16, swizzled),
// (2) GRU via MFMA on those 32 nodes. h ping-pong: read h_in, write h_out.
__global__ __launch_bounds__(256) void layer_kernel(
    const unsigned short* __restrict__ h_in, unsigned short* __restrict__ h_out,
    const int* __restrict__ row_ptr, const int2* __restrict__ csr_sw,
    const unsigned short* __restrict__ Wfuse_p, const unsigned short* __restrict__ Whh_p,
    const float* __restrict__ b_ih, const float* __restrict__ b_hh)
{
  __shared__ uint4 smem[4][32][16];   // [wave][node][16B-chunk], XOR-swizzled; 32 KB
  const int lane = threadIdx.x & 63;
  const int wave = threadIdx.x >> 6;
  const int node0 = blockIdx.x * 128 + wave * 32;
  if (node0 >= NN) return;            // NN % 32 == 0: waves fully in or out

  // ---- phase 1: aggregate 32 nodes (wave-private LDS region; no barrier) ----
  {
    const int q = lane >> 4;          // quarter 0..3
    const int t = lane & 15;
    for (int nn = 0; nn < 32; ++nn) {
      const int node = node0 + nn;
      const int beg = row_ptr[node], end = row_ptr[node + 1];
      const int last = end - 1;
      float acc[8] = {0.f, 0.f, 0.f, 0.f, 0.f, 0.f, 0.f, 0.f};
      for (int j = beg; j < end; j += 16) {
        const int e0 = j + q, e1 = j + 4 + q, e2 = j + 8 + q, e3 = j + 12 + q;
        const int i0 = min(e0, last), i1 = min(e1, last);
        const int i2 = min(e2, last), i3 = min(e3, last);
        const int2 r0 = csr_sw[i0], r1 = csr_sw[i1], r2 = csr_sw[i2], r3 = csr_sw[i3];
        const float w0 = (e0 < end) ? __int_as_float(r0.y) : 0.0f;
        const float w1 = (e1 < end) ? __int_as_float(r1.y) : 0.0f;
        const float w2 = (e2 < end) ? __int_as_float(r2.y) : 0.0f;
        const float w3 = (e3 < end) ? __int_as_float(r3.y) : 0.0f;
        const uint4 u0 = *(const uint4*)(h_in + (size_t)r0.x * CC + t * 8);
        const uint4 u1 = *(const uint4*)(h_in + (size_t)r1.x * CC + t * 8);
        const uint4 u2 = *(const uint4*)(h_in + (size_t)r2.x * CC + t * 8);
        const uint4 u3 = *(const uint4*)(h_in + (size_t)r3.x * CC + t * 8);
        acc[0] = fmaf(bflo(u0.x), w0, acc[0]); acc[1] = fmaf(bfhi(u0.x), w0, acc[1]);
        acc[2] = fmaf(bflo(u0.y), w0, acc[2]); acc[3] = fmaf(bfhi(u0.y), w0, acc[3]);
        acc[4] = fmaf(bflo(u0.z), w0, acc[4]); acc[5] = fmaf(bfhi(u0.z), w0, acc[5]);
        acc[6] = fmaf(bflo(u0.w), w0, acc[6]); acc[7] = fmaf(bfhi(u0.w), w0, acc[7]);
        acc[0] = fmaf(bflo(u1.x), w1, acc[0]); acc[1] = fmaf(bfhi(u1.x), w1, acc[1]);
        acc[2] = fmaf(bflo(u1.y), w1, acc[2]); acc[3] = fmaf(bfhi(u1.y), w1, acc[3]);
        acc[4] = fmaf(bflo(u1.z), w1, acc[4]); acc[5] = fmaf(bfhi(u1.z), w1, acc[5]);
        acc[6] = fmaf(bflo(u1.w), w1, acc[6]); acc[7] = fmaf(bfhi(u1.w), w1, acc[7]);
        acc[0] = fmaf(bflo(u2.x), w2, acc[0]); acc[1] = fmaf(bfhi(u2.x), w2, acc[1]);
        acc[2] = fmaf(bflo(u2.y), w2, acc[2]); acc[3] = fmaf(bfhi(u2.y), w2, acc[3]);
        acc[4] = fmaf(bflo(u2.z), w2, acc[4]); acc[5] = fmaf(bfhi(u2.z), w2, acc[5]);
        acc[6] = fmaf(bflo(u2.w), w2, acc[6]); acc[7] = fmaf(bfhi(u2.w), w2, acc[7]);
        acc[0] = fmaf(bflo(u3.x), w3, acc[0]); acc[1] = fmaf(bfhi(u3.x), w3, acc[1]);
        acc[2] = fmaf(bflo(u3.y), w3, acc[2]); acc[3] = fmaf(bfhi(u3.y), w3, acc[3]);
        acc[4] = fmaf(bflo(u3.z), w3, acc[4]); acc[5] = fmaf(bfhi(u3.z), w3, acc[5]);
        acc[6] = fmaf(bflo(u3.w), w3, acc[6]); acc[7] = fmaf(bfhi(u3.w), w3, acc[7]);
      }
      #pragma unroll
      for (int i = 0; i < 8; ++i) {
        acc[i] += __shfl_xor(acc[i], 16, 64);
        acc[i] += __shfl_xor(acc[i], 32, 64);
      }
      if (q == 0) {
        uint4 o;
        o.x = (unsigned)f2bf(acc[0]) | ((unsigned)f2bf(acc[1]) << 16);
        o.y = (unsigned)f2bf(acc[2]) | ((unsigned)f2bf(acc[3]) << 16);
        o.z = (unsigned)f2bf(acc[4]) | ((unsigned)f2bf(acc[5]) << 16);
        o.w = (unsigned)f2bf(acc[6]) | ((unsigned)f2bf(acc[7]) << 16);
        smem[wave][nn][t ^ (nn & 15)] = o;   // chunk t = channels t*8..t*8+7
      }
    }
  }

  // ---- phase 2: GRU on the same 32 nodes (A_agg from LDS, A_h from global) ----
  const int col16 = lane & 15, grp = lane >> 4;

  bf16x8 aA[2][4], aH[2][4];
  #pragma unroll
  for (int t = 0; t < 2; ++t) {
    const int n = t * 16 + col16;     // node index within wave's 32
    const unsigned short* hrow = h_in + (size_t)(node0 + n) * CC + grp * 8;
    #pragma unroll
    for (int ks = 0; ks < 4; ++ks) {
      uint4 v = smem[wave][n][(grp + 4 * ks) ^ (n & 15)];
      aA[t][ks] = *(bf16x8*)&v;
      aH[t][ks] = *(const bf16x8*)(hrow + ks * 32);
    }
  }

  const f32x4 z4 = {0.f, 0.f, 0.f, 0.f};

  #pragma unroll
  for (int cb = 0; cb < 8; ++cb) {
    f32x4 air[2] = {z4, z4}, ahr[2] = {z4, z4};
    f32x4 aiz[2] = {z4, z4}, ahz[2] = {z4, z4};
    f32x4 ain[2] = {z4, z4}, ahn[2] = {z4, z4};
    #pragma unroll
    for (int ks = 0; ks < 4; ++ks) {
      const size_t or_ = (size_t)((cb * 4 + ks) * 64 + lane) * 8;
      const size_t oz_ = (size_t)(((8 + cb) * 4 + ks) * 64 + lane) * 8;
      const size_t on_ = (size_t)(((16 + cb) * 4 + ks) * 64 + lane) * 8;
      bf16x8 bir = *(const bf16x8*)(Wfuse_p + or_);
      bf16x8 bhr = *(const bf16x8*)(Whh_p + or_);
      bf16x8 biz = *(const bf16x8*)(Wfuse_p + oz_);
      bf16x8 bhz = *(const bf16x8*)(Whh_p + oz_);
      bf16x8 bin = *(const bf16x8*)(Wfuse_p + on_);
      bf16x8 bhn = *(const bf16x8*)(Whh_p + on_);
      #pragma unroll
      for (int t = 0; t < 2; ++t) {
        air[t] = __builtin_amdgcn_mfma_f32_16x16x32_bf16(aA[t][ks], bir, air[t], 0, 0, 0);
        ahr[t] = __builtin_amdgcn_mfma_f32_16x16x32_bf16(aH[t][ks], bhr, ahr[t], 0, 0, 0);
        aiz[t] = __builtin_amdgcn_mfma_f32_16x16x32_bf16(aA[t][ks], biz, aiz[t], 0, 0, 0);
        ahz[t] = __builtin_amdgcn_mfma_f32_16x16x32_bf16(aH[t][ks], bhz, ahz[t], 0, 0, 0);
        ain[t] = __builtin_amdgcn_mfma_f32_16x16x32_bf16(aA[t][ks], bin, ain[t], 0, 0, 0);
        ahn[t] = __builtin_amdgcn_mfma_f32_16x16x32_bf16(aH[t][ks], bhn, ahn[t], 0, 0, 0);
      }
    }
    const int o = cb * 16 + col16;
    const float bir_ = b_ih[o],       bhr_ = b_hh[o];
    const float biz_ = b_ih[128 + o], bhz_ = b_hh[128 + o];
    const float bin_ = b_ih[256 + o], bhn_ = b_hh[256 + o];
    #pragma unroll
    for (int t = 0; t < 2; ++t) {
      #pragma unroll
      for (int r = 0; r < 4; ++r) {
        float rr = sigmoidf_(air[t][r] + ahr[t][r] + bir_ + bhr_);
        float zz = sigmoidf_(aiz[t][r] + ahz[t][r] + biz_ + bhz_);
        float nn = tanhf_(ain[t][r] + bin_ + rr * (ahn[t][r] + bhn_));
        size_t idx = (size_t)(node0 + t * 16 + grp * 4 + r) * CC + o;
        float ho = bf2f(h_in[idx]);
        h_out[idx] = f2bf((1.0f - zz) * nn + zz * ho);
      }
    }
  }
}

// out[batch[n]] += h[n] . W_prop + b_prop   (wave per node; bf16 h)
__global__ __launch_bounds__(256) void prop_kernel(
    const unsigned short* __restrict__ h_bf, const int* __restrict__ batch,
    const float* __restrict__ Wp, const float* __restrict__ bp,
    float* __restrict__ out)
{
  const int lane = threadIdx.x & 63;
  const int wid = (blockIdx.x * blockDim.x + threadIdx.x) >> 6;
  const int nw = (gridDim.x * blockDim.x) >> 6;
  for (int node = wid; node < NN; node += nw) {
    unsigned int u = *(const unsigned int*)(h_bf + (size_t)node * CC + 2 * lane);
    float v = bflo(u) * Wp[2 * lane] + bfhi(u) * Wp[2 * lane + 1];
    #pragma unroll
    for (int off = 32; off > 0; off >>= 1) v += __shfl_down(v, off, 64);
    if (lane == 0) atomicAdd(&out[batch[node]], v + bp[0]);
  }
}

extern "C" void kernel_launch(void* const* d_in, const int* in_sizes, int n_in,
                              void* d_out, int out_size, void* d_ws, size_t ws_size,
                              hipStream_t stream)
{
  const float* x      = (const float*)d_in[0];
  const int*   eidx   = (const int*)d_in[1];
  const float* ew     = (const float*)d_in[2];
  const int*   batch  = (const int*)d_in[3];
  const float* W_emb  = (const float*)d_in[4];
  const float* b_emb  = (const float*)d_in[5];
  const float* W      = (const float*)d_in[6];
  const float* W_ih   = (const float*)d_in[7];
  const float* W_hh   = (const float*)d_in[8];
  const float* b_ih   = (const float*)d_in[9];
  const float* b_hh   = (const float*)d_in[10];
  const float* W_prop = (const float*)d_in[11];
  const float* b_prop = (const float*)d_in[12];
  float* out = (float*)d_out;

  // workspace layout (~78 MB)
  char* p = (char*)d_ws;
  unsigned short* h0    = (unsigned short*)p; p += (size_t)NN * CC * sizeof(short);  // 25.6 MB
  unsigned short* h1    = (unsigned short*)p; p += (size_t)NN * CC * sizeof(short);  // 25.6 MB
  int2* csr_sw          = (int2*)p;           p += (size_t)EE * sizeof(int2);        // 12.8 MB
  int2* bucket          = (int2*)p;           p += (size_t)EE * sizeof(int2);        // 12.8 MB
  unsigned short* Wfuse_p = (unsigned short*)p; p += (size_t)LL * 49152 * sizeof(short);
  unsigned short* Whh_p = (unsigned short*)p; p += (size_t)49152 * sizeof(short);
  int* deg     = (int*)p;                     p += (size_t)(NN + 256) * sizeof(int);
  int* row_ptr = (int*)p;                     p += (size_t)(NN + 256) * sizeof(int);
  int* bcur    = (int*)p;                     p += (size_t)(NBUCKET + 64) * sizeof(int);
  int* bsum    = (int*)p;                     p += 1024 * sizeof(int);

  const int NB_SCAN = (NN + 1023) / 1024;   // 98
  const int EB = (EE + 255) / 256;          // 6250
  const int MB2 = (NN + 127) / 128;         // 782

  // ---- weight prepack ----
  pack_kernel<<<192, 256, 0, stream>>>(W_hh, Whh_p);
  for (int l = 0; l < LL; ++l)
    fuse_pack_kernel<<<192, 256, 0, stream>>>(W + (size_t)l * CC * CC, W_ih,
                                              Wfuse_p + (size_t)l * 49152);

  // ---- CSR build ----
  hipMemsetAsync(deg, 0, (size_t)NN * sizeof(int), stream);
  hist_kernel<<<EB, 256, 0, stream>>>(eidx, deg);
  scan1_kernel<<<NB_SCAN, 256, 0, stream>>>(deg, bsum);
  scan2_kernel<<<1, 64, 0, stream>>>(bsum, NB_SCAN);
  scan3_kernel<<<NB_SCAN, 256, 0, stream>>>(deg, bsum, row_ptr);
  bcur_init_kernel<<<(NBUCKET + 255) / 256, 256, 0, stream>>>(row_ptr, bcur);
  fill_bucket_kernel<<<EB, 256, 0, stream>>>(eidx, ew, bcur, bucket);
  fill_csr_kernel<<<NBUCKET, 128, 0, stream>>>(row_ptr, bucket, csr_sw);

  // ---- main pipeline (h ping-pong: layer l reads h[l%2], writes h[(l+1)%2]) ----
  embed_kernel<<<NN, 128, 0, stream>>>(x, W_emb, b_emb, h0);

  unsigned short* hin = h0;
  unsigned short* hout = h1;
  for (int l = 0; l < LL; ++l) {
    layer_kernel<<<MB2, 256, 0, stream>>>(hin, hout, row_ptr, csr_sw,
                                          Wfuse_p + (size_t)l * 49152, Whh_p, b_ih, b_hh);
    unsigned short* tmp = hin; hin = hout; hout = tmp;
  }

  hipMemsetAsync(d_out, 0, (size_t)GG * sizeof(float), stream);
  prop_kernel<<<2048, 256, 0, stream>>>(hin, batch, W_prop, b_prop, out);
}

// Round 10
// 945.715 us; speedup vs baseline: 1.1989x; 1.1989x over previous
//
#include <hip/hip_runtime.h>

#define NN 100000
#define CC 128
#define EE 1600000
#define GG 1024
#define LL 5
#define NBUCKET 12500        // NN/8; 8 nodes per bucket

typedef __attribute__((ext_vector_type(8))) short bf16x8;
typedef __attribute__((ext_vector_type(4))) float f32x4;

__device__ __forceinline__ float sigmoidf_(float x) { return 1.0f / (1.0f + __expf(-x)); }
__device__ __forceinline__ float tanhf_(float x) {
  float xx = fminf(15.0f, fmaxf(-15.0f, x));
  float t = __expf(-2.0f * xx);
  return (1.0f - t) / (1.0f + t);
}
__device__ __forceinline__ unsigned short f2bf(float x) {
  unsigned int u = __float_as_uint(x);
  return (unsigned short)((u + 0x7fffu + ((u >> 16) & 1u)) >> 16);
}
__device__ __forceinline__ float bflo(unsigned int u) { return __uint_as_float(u << 16); }
__device__ __forceinline__ float bfhi(unsigned int u) { return __uint_as_float(u & 0xffff0000u); }
__device__ __forceinline__ float bf2f(unsigned short v) { return __uint_as_float((unsigned)v << 16); }

// ---------------- weight prepack ----------------
// Packed B-fragment layout: element (k, c) at t = ((cb*4+ks)*64 + l)*8 + i
// with k = ks*32 + 8*(l>>4) + i, c = cb*16 + (l&15).

__global__ __launch_bounds__(256) void pack_kernel(
    const float* __restrict__ src, unsigned short* __restrict__ dst)
{
  int t = blockIdx.x * 256 + threadIdx.x;           // 49152
  int i = t & 7, l = (t >> 3) & 63, q = t >> 9;
  int ks = q & 3, cb = q >> 2;
  int k = ks * 32 + 8 * (l >> 4) + i;
  int c = cb * 16 + (l & 15);
  dst[t] = f2bf(src[(size_t)c * CC + k]);
}

// Wfuse_l[k][c] = sum_j W_l[k][j] * W_ih[c][j]
__global__ __launch_bounds__(256) void fuse_pack_kernel(
    const float* __restrict__ Wl, const float* __restrict__ W_ih,
    unsigned short* __restrict__ dst)
{
  int t = blockIdx.x * 256 + threadIdx.x;           // 49152 per layer
  int i = t & 7, l = (t >> 3) & 63, q = t >> 9;
  int ks = q & 3, cb = q >> 2;
  int k = ks * 32 + 8 * (l >> 4) + i;
  int c = cb * 16 + (l & 15);
  const float* wl = Wl + (size_t)k * CC;
  const float* wi = W_ih + (size_t)c * CC;
  float acc = 0.f;
  #pragma unroll 8
  for (int j = 0; j < CC; ++j) acc = fmaf(wl[j], wi[j], acc);
  dst[t] = f2bf(acc);
}

// ---------------- CSR build (once per call) ----------------

__global__ __launch_bounds__(256) void hist_kernel(const int* __restrict__ eidx,
                                                   int* __restrict__ deg)
{
  int e = blockIdx.x * blockDim.x + threadIdx.x;
  if (e < EE) atomicAdd(&deg[eidx[EE + e]], 1);
}

__global__ __launch_bounds__(256) void scan1_kernel(const int* __restrict__ deg,
                                                    int* __restrict__ bsum)
{
  __shared__ int red[4];
  int base = blockIdx.x * 1024 + threadIdx.x * 4;
  int s = 0;
  #pragma unroll
  for (int i = 0; i < 4; ++i) { int idx = base + i; if (idx < NN) s += deg[idx]; }
  #pragma unroll
  for (int off = 32; off; off >>= 1) s += __shfl_down(s, off, 64);
  if ((threadIdx.x & 63) == 0) red[threadIdx.x >> 6] = s;
  __syncthreads();
  if (threadIdx.x == 0) bsum[blockIdx.x] = red[0] + red[1] + red[2] + red[3];
}

__global__ void scan2_kernel(int* __restrict__ bsum, int nb)
{
  if (threadIdx.x == 0 && blockIdx.x == 0) {
    int acc = 0;
    for (int i = 0; i < nb; ++i) { int v = bsum[i]; bsum[i] = acc; acc += v; }
  }
}

__global__ __launch_bounds__(256) void scan3_kernel(const int* __restrict__ deg,
                                                    const int* __restrict__ bsum,
                                                    int* __restrict__ row_ptr)
{
  __shared__ int ts[256];
  const int tid = threadIdx.x;
  const int base = blockIdx.x * 1024 + tid * 4;
  int v[4]; int s = 0;
  #pragma unroll
  for (int i = 0; i < 4; ++i) { int idx = base + i; v[i] = (idx < NN) ? deg[idx] : 0; s += v[i]; }
  ts[tid] = s; __syncthreads();
  for (int off = 1; off < 256; off <<= 1) {
    int t = (tid >= off) ? ts[tid - off] : 0;
    __syncthreads();
    ts[tid] += t;
    __syncthreads();
  }
  int excl = bsum[blockIdx.x] + ts[tid] - s;
  #pragma unroll
  for (int i = 0; i < 4; ++i) {
    int idx = base + i;
    if (idx < NN) { row_ptr[idx] = excl; excl += v[i]; }
  }
  if (blockIdx.x == 0 && tid == 0) row_ptr[NN] = EE;
}

__global__ void bcur_init_kernel(const int* __restrict__ row_ptr, int* __restrict__ bcur)
{
  int b = blockIdx.x * blockDim.x + threadIdx.x;
  if (b < NBUCKET) bcur[b] = row_ptr[b * 8];
}

// phase 1: append edges into dst-bucket span (12500 cursors, low contention)
__global__ __launch_bounds__(256) void fill_bucket_kernel(
    const int* __restrict__ eidx, const float* __restrict__ ew,
    int* __restrict__ bcur, int2* __restrict__ bucket)
{
  int e = blockIdx.x * blockDim.x + threadIdx.x;
  if (e < EE) {
    int d = eidx[EE + e];
    int p = atomicAdd(&bcur[d >> 3], 1);
    bucket[p] = make_int2(eidx[e] | ((d & 7) << 17), __float_as_int(ew[e]));
  }
}

// phase 2: one block per bucket; 8 LDS cursors; scatter within ~1KB L2 span
__global__ __launch_bounds__(128) void fill_csr_kernel(
    const int* __restrict__ row_ptr, const int2* __restrict__ bucket,
    int2* __restrict__ csr_sw)
{
  __shared__ int cur[8];
  const int b = blockIdx.x;
  const int tid = threadIdx.x;
  if (tid < 8) cur[tid] = row_ptr[b * 8 + tid];
  __syncthreads();
  const int start = row_ptr[b * 8];
  const int stop  = row_ptr[b * 8 + 8];
  for (int j = start + tid; j < stop; j += 128) {
    int2 r = bucket[j];
    unsigned u = (unsigned)r.x;
    int p = atomicAdd(&cur[u >> 17], 1);
    csr_sw[p] = make_int2((int)(u & 0x1FFFFu), r.y);
  }
}

// ---------------- main pipeline ----------------

// h0 = x @ W_emb + b_emb; bf16 state
__global__ __launch_bounds__(128) void embed_kernel(
    const float* __restrict__ x, const float* __restrict__ W_emb,
    const float* __restrict__ b_emb, unsigned short* __restrict__ h_bf)
{
  const int node = blockIdx.x;
  const int c = threadIdx.x;
  float acc = b_emb[c];
  #pragma unroll
  for (int k = 0; k < 32; ++k)
    acc = fmaf(x[node * 32 + k], W_emb[k * CC + c], acc);
  h_bf[(size_t)node * CC + c] = f2bf(acc);
}

// CSR gather: TWO nodes per wave, 32 edges in flight (16 per node).
// 4 quarters x 16 lanes; quarter q handles edges j+q, j+4+q, j+8+q, j+12+q.
__global__ __launch_bounds__(256) void aggregate_kernel(
    const unsigned short* __restrict__ h_bf, const int* __restrict__ row_ptr,
    const int2* __restrict__ csr_sw, unsigned short* __restrict__ agg_bf)
{
  const int lane = threadIdx.x & 63;
  const int wid = (blockIdx.x * blockDim.x + threadIdx.x) >> 6;
  const int na = wid * 2;
  if (na >= NN) return;
  const int nb = na + 1;
  const int q = lane >> 4;
  const int t = lane & 15;

  const int bega = row_ptr[na], enda = row_ptr[na + 1], endb = row_ptr[nb + 1];
  const int lasta = min(max(enda - 1, 0), EE - 1);
  const int lastb = min(max(endb - 1, 0), EE - 1);

  float acca[8] = {0.f, 0.f, 0.f, 0.f, 0.f, 0.f, 0.f, 0.f};
  float accb[8] = {0.f, 0.f, 0.f, 0.f, 0.f, 0.f, 0.f, 0.f};

  int ja = bega, jb = enda;           // enda == row_ptr[nb]
  while (ja < enda || jb < endb) {
    const int a0 = ja + q, a1 = ja + 4 + q, a2 = ja + 8 + q, a3 = ja + 12 + q;
    const int b0 = jb + q, b1 = jb + 4 + q, b2 = jb + 8 + q, b3 = jb + 12 + q;
    const int2 ra0 = csr_sw[min(a0, lasta)], ra1 = csr_sw[min(a1, lasta)];
    const int2 ra2 = csr_sw[min(a2, lasta)], ra3 = csr_sw[min(a3, lasta)];
    const int2 rb0 = csr_sw[min(b0, lastb)], rb1 = csr_sw[min(b1, lastb)];
    const int2 rb2 = csr_sw[min(b2, lastb)], rb3 = csr_sw[min(b3, lastb)];
    const uint4 ua0 = *(const uint4*)(h_bf + (size_t)ra0.x * CC + t * 8);
    const uint4 ua1 = *(const uint4*)(h_bf + (size_t)ra1.x * CC + t * 8);
    const uint4 ua2 = *(const uint4*)(h_bf + (size_t)ra2.x * CC + t * 8);
    const uint4 ua3 = *(const uint4*)(h_bf + (size_t)ra3.x * CC + t * 8);
    const uint4 ub0 = *(const uint4*)(h_bf + (size_t)rb0.x * CC + t * 8);
    const uint4 ub1 = *(const uint4*)(h_bf + (size_t)rb1.x * CC + t * 8);
    const uint4 ub2 = *(const uint4*)(h_bf + (size_t)rb2.x * CC + t * 8);
    const uint4 ub3 = *(const uint4*)(h_bf + (size_t)rb3.x * CC + t * 8);
    const float wa0 = (a0 < enda) ? __int_as_float(ra0.y) : 0.0f;
    const float wa1 = (a1 < enda) ? __int_as_float(ra1.y) : 0.0f;
    const float wa2 = (a2 < enda) ? __int_as_float(ra2.y) : 0.0f;
    const float wa3 = (a3 < enda) ? __int_as_float(ra3.y) : 0.0f;
    const float wb0 = (b0 < endb) ? __int_as_float(rb0.y) : 0.0f;
    const float wb1 = (b1 < endb) ? __int_as_float(rb1.y) : 0.0f;
    const float wb2 = (b2 < endb) ? __int_as_float(rb2.y) : 0.0f;
    const float wb3 = (b3 < endb) ? __int_as_float(rb3.y) : 0.0f;

    acca[0] = fmaf(bflo(ua0.x), wa0, acca[0]); acca[1] = fmaf(bfhi(ua0.x), wa0, acca[1]);
    acca[2] = fmaf(bflo(ua0.y), wa0, acca[2]); acca[3] = fmaf(bfhi(ua0.y), wa0, acca[3]);
    acca[4] = fmaf(bflo(ua0.z), wa0, acca[4]); acca[5] = fmaf(bfhi(ua0.z), wa0, acca[5]);
    acca[6] = fmaf(bflo(ua0.w), wa0, acca[6]); acca[7] = fmaf(bfhi(ua0.w), wa0, acca[7]);
    acca[0] = fmaf(bflo(ua1.x), wa1, acca[0]); acca[1] = fmaf(bfhi(ua1.x), wa1, acca[1]);
    acca[2] = fmaf(bflo(ua1.y), wa1, acca[2]); acca[3] = fmaf(bfhi(ua1.y), wa1, acca[3]);
    acca[4] = fmaf(bflo(ua1.z), wa1, acca[4]); acca[5] = fmaf(bfhi(ua1.z), wa1, acca[5]);
    acca[6] = fmaf(bflo(ua1.w), wa1, acca[6]); acca[7] = fmaf(bfhi(ua1.w), wa1, acca[7]);
    acca[0] = fmaf(bflo(ua2.x), wa2, acca[0]); acca[1] = fmaf(bfhi(ua2.x), wa2, acca[1]);
    acca[2] = fmaf(bflo(ua2.y), wa2, acca[2]); acca[3] = fmaf(bfhi(ua2.y), wa2, acca[3]);
    acca[4] = fmaf(bflo(ua2.z), wa2, acca[4]); acca[5] = fmaf(bfhi(ua2.z), wa2, acca[5]);
    acca[6] = fmaf(bflo(ua2.w), wa2, acca[6]); acca[7] = fmaf(bfhi(ua2.w), wa2, acca[7]);
    acca[0] = fmaf(bflo(ua3.x), wa3, acca[0]); acca[1] = fmaf(bfhi(ua3.x), wa3, acca[1]);
    acca[2] = fmaf(bflo(ua3.y), wa3, acca[2]); acca[3] = fmaf(bfhi(ua3.y), wa3, acca[3]);
    acca[4] = fmaf(bflo(ua3.z), wa3, acca[4]); acca[5] = fmaf(bfhi(ua3.z), wa3, acca[5]);
    acca[6] = fmaf(bflo(ua3.w), wa3, acca[6]); acca[7] = fmaf(bfhi(ua3.w), wa3, acca[7]);

    accb[0] = fmaf(bflo(ub0.x), wb0, accb[0]); accb[1] = fmaf(bfhi(ub0.x), wb0, accb[1]);
    accb[2] = fmaf(bflo(ub0.y), wb0, accb[2]); accb[3] = fmaf(bfhi(ub0.y), wb0, accb[3]);
    accb[4] = fmaf(bflo(ub0.z), wb0, accb[4]); accb[5] = fmaf(bfhi(ub0.z), wb0, accb[5]);
    accb[6] = fmaf(bflo(ub0.w), wb0, accb[6]); accb[7] = fmaf(bfhi(ub0.w), wb0, accb[7]);
    accb[0] = fmaf(bflo(ub1.x), wb1, accb[0]); accb[1] = fmaf(bfhi(ub1.x), wb1, accb[1]);
    accb[2] = fmaf(bflo(ub1.y), wb1, accb[2]); accb[3] = fmaf(bfhi(ub1.y), wb1, accb[3]);
    accb[4] = fmaf(bflo(ub1.z), wb1, accb[4]); accb[5] = fmaf(bfhi(ub1.z), wb1, accb[5]);
    accb[6] = fmaf(bflo(ub1.w), wb1, accb[6]); accb[7] = fmaf(bfhi(ub1.w), wb1, accb[7]);
    accb[0] = fmaf(bflo(ub2.x), wb2, accb[0]); accb[1] = fmaf(bfhi(ub2.x), wb2, accb[1]);
    accb[2] = fmaf(bflo(ub2.y), wb2, accb[2]); accb[3] = fmaf(bfhi(ub2.y), wb2, accb[3]);
    accb[4] = fmaf(bflo(ub2.z), wb2, accb[4]); accb[5] = fmaf(bfhi(ub2.z), wb2, accb[5]);
    accb[6] = fmaf(bflo(ub2.w), wb2, accb[6]); accb[7] = fmaf(bfhi(ub2.w), wb2, accb[7]);
    accb[0] = fmaf(bflo(ub3.x), wb3, accb[0]); accb[1] = fmaf(bfhi(ub3.x), wb3, accb[1]);
    accb[2] = fmaf(bflo(ub3.y), wb3, accb[2]); accb[3] = fmaf(bfhi(ub3.y), wb3, accb[3]);
    accb[4] = fmaf(bflo(ub3.z), wb3, accb[4]); accb[5] = fmaf(bfhi(ub3.z), wb3, accb[5]);
    accb[6] = fmaf(bflo(ub3.w), wb3, accb[6]); accb[7] = fmaf(bfhi(ub3.w), wb3, accb[7]);

    ja += 16; jb += 16;
  }

  #pragma unroll
  for (int i = 0; i < 8; ++i) {
    acca[i] += __shfl_xor(acca[i], 16, 64);
    acca[i] += __shfl_xor(acca[i], 32, 64);
    accb[i] += __shfl_xor(accb[i], 16, 64);
    accb[i] += __shfl_xor(accb[i], 32, 64);
  }

  if (q == 0) {
    uint4 o;
    o.x = (unsigned)f2bf(acca[0]) | ((unsigned)f2bf(acca[1]) << 16);
    o.y = (unsigned)f2bf(acca[2]) | ((unsigned)f2bf(acca[3]) << 16);
    o.z = (unsigned)f2bf(acca[4]) | ((unsigned)f2bf(acca[5]) << 16);
    o.w = (unsigned)f2bf(acca[6]) | ((unsigned)f2bf(acca[7]) << 16);
    *(uint4*)(agg_bf + (size_t)na * CC + t * 8) = o;
  } else if (q == 1) {
    uint4 o;
    o.x = (unsigned)f2bf(accb[0]) | ((unsigned)f2bf(accb[1]) << 16);
    o.y = (unsigned)f2bf(accb[2]) | ((unsigned)f2bf(accb[3]) << 16);
    o.z = (unsigned)f2bf(accb[4]) | ((unsigned)f2bf(accb[5]) << 16);
    o.w = (unsigned)f2bf(accb[6]) | ((unsigned)f2bf(accb[7]) << 16);
    *(uint4*)(agg_bf + (size_t)nb * CC + t * 8) = o;
  }
}

// GRU via MFMA with LDS-staged weights: per cb, 4 waves share one L2 read of the
// 24KB fragment set. h ping-pong (tail waves clamp to node 0: identical writes).
__global__ __launch_bounds__(256) void gru_kernel(
    const unsigned short* __restrict__ agg_bf,
    const unsigned short* __restrict__ h_in, unsigned short* __restrict__ h_out,
    const unsigned short* __restrict__ Wfuse_p, const unsigned short* __restrict__ Whh_p,
    const float* __restrict__ b_ih, const float* __restrict__ b_hh)
{
  __shared__ uint4 wbuf[2][3][4][64];   // [mat][gate][ks][lane] = 24 KB
  const int tid = threadIdx.x;
  const int lane = tid & 63;
  const int wave = tid >> 6;
  int node0 = blockIdx.x * 128 + wave * 32;
  if (node0 + 32 > NN) node0 = 0;       // tail waves redo nodes 0..31 (benign)
  const int col16 = lane & 15, grp = lane >> 4;

  bf16x8 aA[2][4], aH[2][4];
  #pragma unroll
  for (int t = 0; t < 2; ++t) {
    const unsigned short* arow = agg_bf + (size_t)(node0 + t * 16 + col16) * CC + grp * 8;
    const unsigned short* hrow = h_in  + (size_t)(node0 + t * 16 + col16) * CC + grp * 8;
    #pragma unroll
    for (int ks = 0; ks < 4; ++ks) {
      aA[t][ks] = *(const bf16x8*)(arow + ks * 32);
      aH[t][ks] = *(const bf16x8*)(hrow + ks * 32);
    }
  }

  const f32x4 z4 = {0.f, 0.f, 0.f, 0.f};
  const int sks = tid >> 6, slane = tid & 63;   // staging coords (ks=wave, lane)

  for (int cb = 0; cb < 8; ++cb) {
    __syncthreads();      // previous cb's LDS reads complete before overwrite
    // stage: gate 0=r(cb), 1=z(8+cb), 2=n(16+cb); 6 × 16B per thread
    #pragma unroll
    for (int g = 0; g < 3; ++g) {
      const size_t f = (size_t)(((cb + 8 * g) * 4 + sks) * 64 + slane) * 8;
      wbuf[0][g][sks][slane] = *(const uint4*)(Wfuse_p + f);
      wbuf[1][g][sks][slane] = *(const uint4*)(Whh_p + f);
    }
    __syncthreads();

    f32x4 air[2] = {z4, z4}, ahr[2] = {z4, z4};
    f32x4 aiz[2] = {z4, z4}, ahz[2] = {z4, z4};
    f32x4 ain[2] = {z4, z4}, ahn[2] = {z4, z4};
    #pragma unroll
    for (int ks = 0; ks < 4; ++ks) {
      bf16x8 bir = *(const bf16x8*)&wbuf[0][0][ks][lane];
      bf16x8 bhr = *(const bf16x8*)&wbuf[1][0][ks][lane];
      bf16x8 biz = *(const bf16x8*)&wbuf[0][1][ks][lane];
      bf16x8 bhz = *(const bf16x8*)&wbuf[1][1][ks][lane];
      bf16x8 bin = *(const bf16x8*)&wbuf[0][2][ks][lane];
      bf16x8 bhn = *(const bf16x8*)&wbuf[1][2][ks][lane];
      #pragma unroll
      for (int t = 0; t < 2; ++t) {
        air[t] = __builtin_amdgcn_mfma_f32_16x16x32_bf16(aA[t][ks], bir, air[t], 0, 0, 0);
        ahr[t] = __builtin_amdgcn_mfma_f32_16x16x32_bf16(aH[t][ks], bhr, ahr[t], 0, 0, 0);
        aiz[t] = __builtin_amdgcn_mfma_f32_16x16x32_bf16(aA[t][ks], biz, aiz[t], 0, 0, 0);
        ahz[t] = __builtin_amdgcn_mfma_f32_16x16x32_bf16(aH[t][ks], bhz, ahz[t], 0, 0, 0);
        ain[t] = __builtin_amdgcn_mfma_f32_16x16x32_bf16(aA[t][ks], bin, ain[t], 0, 0, 0);
        ahn[t] = __builtin_amdgcn_mfma_f32_16x16x32_bf16(aH[t][ks], bhn, ahn[t], 0, 0, 0);
      }
    }
    const int o = cb * 16 + col16;
    const float bir_ = b_ih[o],       bhr_ = b_hh[o];
    const float biz_ = b_ih[128 + o], bhz_ = b_hh[128 + o];
    const float bin_ = b_ih[256 + o], bhn_ = b_hh[256 + o];
    #pragma unroll
    for (int t = 0; t < 2; ++t) {
      #pragma unroll
      for (int r = 0; r < 4; ++r) {
        float rr = sigmoidf_(air[t][r] + ahr[t][r] + bir_ + bhr_);
        float zz = sigmoidf_(aiz[t][r] + ahz[t][r] + biz_ + bhz_);
        float nn = tanhf_(ain[t][r] + bin_ + rr * (ahn[t][r] + bhn_));
        size_t idx = (size_t)(node0 + t * 16 + grp * 4 + r) * CC + o;
        float ho = bf2f(h_in[idx]);
        h_out[idx] = f2bf((1.0f - zz) * nn + zz * ho);
      }
    }
  }
}

// out[batch[n]] += h[n] . W_prop + b_prop   (wave per node; bf16 h)
__global__ __launch_bounds__(256) void prop_kernel(
    const unsigned short* __restrict__ h_bf, const int* __restrict__ batch,
    const float* __restrict__ Wp, const float* __restrict__ bp,
    float* __restrict__ out)
{
  const int lane = threadIdx.x & 63;
  const int wid = (blockIdx.x * blockDim.x + threadIdx.x) >> 6;
  const int nw = (gridDim.x * blockDim.x) >> 6;
  for (int node = wid; node < NN; node += nw) {
    unsigned int u = *(const unsigned int*)(h_bf + (size_t)node * CC + 2 * lane);
    float v = bflo(u) * Wp[2 * lane] + bfhi(u) * Wp[2 * lane + 1];
    #pragma unroll
    for (int off = 32; off > 0; off >>= 1) v += __shfl_down(v, off, 64);
    if (lane == 0) atomicAdd(&out[batch[node]], v + bp[0]);
  }
}

extern "C" void kernel_launch(void* const* d_in, const int* in_sizes, int n_in,
                              void* d_out, int out_size, void* d_ws, size_t ws_size,
                              hipStream_t stream)
{
  const float* x      = (const float*)d_in[0];
  const int*   eidx   = (const int*)d_in[1];
  const float* ew     = (const float*)d_in[2];
  const int*   batch  = (const int*)d_in[3];
  const float* W_emb  = (const float*)d_in[4];
  const float* b_emb  = (const float*)d_in[5];
  const float* W      = (const float*)d_in[6];
  const float* W_ih   = (const float*)d_in[7];
  const float* W_hh   = (const float*)d_in[8];
  const float* b_ih   = (const float*)d_in[9];
  const float* b_hh   = (const float*)d_in[10];
  const float* W_prop = (const float*)d_in[11];
  const float* b_prop = (const float*)d_in[12];
  float* out = (float*)d_out;

  // workspace layout (~104 MB)
  char* p = (char*)d_ws;
  unsigned short* h0    = (unsigned short*)p; p += (size_t)NN * CC * sizeof(short);  // 25.6 MB
  unsigned short* h1    = (unsigned short*)p; p += (size_t)NN * CC * sizeof(short);  // 25.6 MB
  unsigned short* agg   = (unsigned short*)p; p += (size_t)NN * CC * sizeof(short);  // 25.6 MB
  int2* csr_sw          = (int2*)p;           p += (size_t)EE * sizeof(int2);        // 12.8 MB
  int2* bucket          = (int2*)p;           p += (size_t)EE * sizeof(int2);        // 12.8 MB
  unsigned short* Wfuse_p = (unsigned short*)p; p += (size_t)LL * 49152 * sizeof(short);
  unsigned short* Whh_p = (unsigned short*)p; p += (size_t)49152 * sizeof(short);
  int* deg     = (int*)p;                     p += (size_t)(NN + 256) * sizeof(int);
  int* row_ptr = (int*)p;                     p += (size_t)(NN + 256) * sizeof(int);
  int* bcur    = (int*)p;                     p += (size_t)(NBUCKET + 64) * sizeof(int);
  int* bsum    = (int*)p;                     p += 1024 * sizeof(int);

  const int NB_SCAN = (NN + 1023) / 1024;   // 98
  const int EB = (EE + 255) / 256;          // 6250
  const int MB2 = (NN + 127) / 128;         // 782

  // ---- weight prepack ----
  pack_kernel<<<192, 256, 0, stream>>>(W_hh, Whh_p);
  for (int l = 0; l < LL; ++l)
    fuse_pack_kernel<<<192, 256, 0, stream>>>(W + (size_t)l * CC * CC, W_ih,
                                              Wfuse_p + (size_t)l * 49152);

  // ---- CSR build ----
  hipMemsetAsync(deg, 0, (size_t)NN * sizeof(int), stream);
  hist_kernel<<<EB, 256, 0, stream>>>(eidx, deg);
  scan1_kernel<<<NB_SCAN, 256, 0, stream>>>(deg, bsum);
  scan2_kernel<<<1, 64, 0, stream>>>(bsum, NB_SCAN);
  scan3_kernel<<<NB_SCAN, 256, 0, stream>>>(deg, bsum, row_ptr);
  bcur_init_kernel<<<(NBUCKET + 255) / 256, 256, 0, stream>>>(row_ptr, bcur);
  fill_bucket_kernel<<<EB, 256, 0, stream>>>(eidx, ew, bcur, bucket);
  fill_csr_kernel<<<NBUCKET, 128, 0, stream>>>(row_ptr, bucket, csr_sw);

  // ---- main pipeline (h ping-pong) ----
  embed_kernel<<<NN, 128, 0, stream>>>(x, W_emb, b_emb, h0);

  unsigned short* hin = h0;
  unsigned short* hout = h1;
  for (int l = 0; l < LL; ++l) {
    aggregate_kernel<<<12500, 256, 0, stream>>>(hin, row_ptr, csr_sw, agg);
    gru_kernel<<<MB2, 256, 0, stream>>>(agg, hin, hout,
                                        Wfuse_p + (size_t)l * 49152, Whh_p, b_ih, b_hh);
    unsigned short* tmp = hin; hin = hout; hout = tmp;
  }

  hipMemsetAsync(d_out, 0, (size_t)GG * sizeof(float), stream);
  prop_kernel<<<2048, 256, 0, stream>>>(hin, batch, W_prop, b_prop, out);
}

// Round 11
// 886.548 us; speedup vs baseline: 1.2789x; 1.0667x over previous
//
#include <hip/hip_runtime.h>

#define NN 100000
#define CC 128
#define EE 1600000
#define GG 1024
#define LL 5

typedef __attribute__((ext_vector_type(8))) short bf16x8;
typedef __attribute__((ext_vector_type(4))) float f32x4;

__device__ __forceinline__ float sigmoidf_(float x) { return 1.0f / (1.0f + __expf(-x)); }
__device__ __forceinline__ float tanhf_(float x) {
  float xx = fminf(15.0f, fmaxf(-15.0f, x));
  float t = __expf(-2.0f * xx);
  return (1.0f - t) / (1.0f + t);
}
__device__ __forceinline__ unsigned short f2bf(float x) {
  unsigned int u = __float_as_uint(x);
  return (unsigned short)((u + 0x7fffu + ((u >> 16) & 1u)) >> 16);
}
__device__ __forceinline__ float bflo(unsigned int u) { return __uint_as_float(u << 16); }
__device__ __forceinline__ float bfhi(unsigned int u) { return __uint_as_float(u & 0xffff0000u); }
__device__ __forceinline__ float bf2f(unsigned short v) { return __uint_as_float((unsigned)v << 16); }

// ---------------- fused prepack + zero-init kernel (one launch) ----------------
// Packed B-fragment layout: element (k, c) at t = ((cb*4+ks)*64 + l)*8 + i
// with k = ks*32 + 8*(l>>4) + i, c = cb*16 + (l&15).
// blocks [0,192): Whh pack; [192,1152): Wfuse per layer; [1152,1544): zero deg;
// block 1544: zero out.
#define PK_WHH 192
#define PK_FUSE (192 * LL)
#define PK_DEG ((NN + 256 + 255) / 256)   // 392
#define PK_TOTAL (PK_WHH + PK_FUSE + PK_DEG + 1)

__global__ __launch_bounds__(256) void pack_all_kernel(
    const float* __restrict__ W, const float* __restrict__ W_ih,
    const float* __restrict__ W_hh,
    unsigned short* __restrict__ Whh_p, unsigned short* __restrict__ Wfuse_p,
    int* __restrict__ deg, float* __restrict__ out)
{
  const int b = blockIdx.x;
  const int tid = threadIdx.x;
  if (b < PK_WHH) {
    int t = b * 256 + tid;
    int i = t & 7, l = (t >> 3) & 63, q = t >> 9;
    int ks = q & 3, cb = q >> 2;
    int k = ks * 32 + 8 * (l >> 4) + i;
    int c = cb * 16 + (l & 15);
    Whh_p[t] = f2bf(W_hh[(size_t)c * CC + k]);
  } else if (b < PK_WHH + PK_FUSE) {
    int idx = b - PK_WHH;
    int layer = idx / 192;
    int t = (idx % 192) * 256 + tid;
    int i = t & 7, l = (t >> 3) & 63, q = t >> 9;
    int ks = q & 3, cb = q >> 2;
    int k = ks * 32 + 8 * (l >> 4) + i;
    int c = cb * 16 + (l & 15);
    const float* wl = W + (size_t)layer * CC * CC + (size_t)k * CC;
    const float* wi = W_ih + (size_t)c * CC;
    float acc = 0.f;
    #pragma unroll 8
    for (int j = 0; j < CC; ++j) acc = fmaf(wl[j], wi[j], acc);
    Wfuse_p[(size_t)layer * 49152 + t] = f2bf(acc);
  } else if (b < PK_WHH + PK_FUSE + PK_DEG) {
    int i = (b - PK_WHH - PK_FUSE) * 256 + tid;
    if (i < NN + 256) deg[i] = 0;
  } else {
    #pragma unroll
    for (int i = 0; i < 4; ++i) out[i * 256 + tid] = 0.0f;
  }
}

// ---------------- CSR build (once per call) ----------------

__global__ __launch_bounds__(256) void hist_kernel(const int* __restrict__ eidx,
                                                   int* __restrict__ deg)
{
  int e = blockIdx.x * blockDim.x + threadIdx.x;
  if (e < EE) atomicAdd(&deg[eidx[EE + e]], 1);
}

__global__ __launch_bounds__(256) void scan1_kernel(const int* __restrict__ deg,
                                                    int* __restrict__ bsum)
{
  __shared__ int red[4];
  int base = blockIdx.x * 1024 + threadIdx.x * 4;
  int s = 0;
  #pragma unroll
  for (int i = 0; i < 4; ++i) { int idx = base + i; if (idx < NN) s += deg[idx]; }
  #pragma unroll
  for (int off = 32; off; off >>= 1) s += __shfl_down(s, off, 64);
  if ((threadIdx.x & 63) == 0) red[threadIdx.x >> 6] = s;
  __syncthreads();
  if (threadIdx.x == 0) bsum[blockIdx.x] = red[0] + red[1] + red[2] + red[3];
}

// wave-parallel exclusive scan of the 98-entry block-sum array (was serial loop)
__global__ __launch_bounds__(64) void scan2_kernel(int* __restrict__ bsum, int nb)
{
  const int lane = threadIdx.x;
  int carry = 0;
  for (int base = 0; base < nb; base += 64) {
    int i = base + lane;
    int v = (i < nb) ? bsum[i] : 0;
    const int orig = v;
    #pragma unroll
    for (int off = 1; off < 64; off <<= 1) {
      int u = __shfl_up(v, off, 64);
      if (lane >= off) v += u;
    }
    if (i < nb) bsum[i] = v - orig + carry;
    carry += __shfl(v, 63, 64);
  }
}

__global__ __launch_bounds__(256) void scan3_kernel(const int* __restrict__ deg,
                                                    const int* __restrict__ bsum,
                                                    int* __restrict__ row_ptr,
                                                    int* __restrict__ cursor)
{
  __shared__ int ts[256];
  const int tid = threadIdx.x;
  const int base = blockIdx.x * 1024 + tid * 4;
  int v[4]; int s = 0;
  #pragma unroll
  for (int i = 0; i < 4; ++i) { int idx = base + i; v[i] = (idx < NN) ? deg[idx] : 0; s += v[i]; }
  ts[tid] = s; __syncthreads();
  for (int off = 1; off < 256; off <<= 1) {
    int t = (tid >= off) ? ts[tid - off] : 0;
    __syncthreads();
    ts[tid] += t;
    __syncthreads();
  }
  int excl = bsum[blockIdx.x] + ts[tid] - s;
  #pragma unroll
  for (int i = 0; i < 4; ++i) {
    int idx = base + i;
    if (idx < NN) { row_ptr[idx] = excl; cursor[idx] = excl; excl += v[i]; }
  }
  if (blockIdx.x == 0 && tid == 0) row_ptr[NN] = EE;
}

// direct single-phase fill: 100K cursors -> negligible contention; write amp accepted
__global__ __launch_bounds__(256) void fill_kernel(const int* __restrict__ eidx,
                                                   const float* __restrict__ ew,
                                                   int* __restrict__ cursor,
                                                   int2* __restrict__ csr_sw)
{
  int e = blockIdx.x * blockDim.x + threadIdx.x;
  if (e < EE) {
    int d = eidx[EE + e];
    int p = atomicAdd(&cursor[d], 1);
    csr_sw[p] = make_int2(eidx[e], __float_as_int(ew[e]));
  }
}

// ---------------- main pipeline ----------------

// h0 = x @ W_emb + b_emb; bf16 state
__global__ __launch_bounds__(128) void embed_kernel(
    const float* __restrict__ x, const float* __restrict__ W_emb,
    const float* __restrict__ b_emb, unsigned short* __restrict__ h_bf)
{
  const int node = blockIdx.x;
  const int c = threadIdx.x;
  float acc = b_emb[c];
  #pragma unroll
  for (int k = 0; k < 32; ++k)
    acc = fmaf(x[node * 32 + k], W_emb[k * CC + c], acc);
  h_bf[(size_t)node * CC + c] = f2bf(acc);
}

// CSR gather (R8 structure): one node per wave, 16 edges in flight.
__global__ __launch_bounds__(256) void aggregate_kernel(
    const unsigned short* __restrict__ h_bf, const int* __restrict__ row_ptr,
    const int2* __restrict__ csr_sw, unsigned short* __restrict__ agg_bf)
{
  const int lane = threadIdx.x & 63;
  const int node = (blockIdx.x * blockDim.x + threadIdx.x) >> 6;
  if (node >= NN) return;
  const int q = lane >> 4;
  const int t = lane & 15;
  const int beg = row_ptr[node], end = row_ptr[node + 1];

  float acc[8] = {0.f, 0.f, 0.f, 0.f, 0.f, 0.f, 0.f, 0.f};
  const int last = end - 1;

  for (int j = beg; j < end; j += 16) {
    const int e0 = j + q, e1 = j + 4 + q, e2 = j + 8 + q, e3 = j + 12 + q;
    const int i0 = min(e0, last), i1 = min(e1, last);
    const int i2 = min(e2, last), i3 = min(e3, last);
    const int2 r0 = csr_sw[i0], r1 = csr_sw[i1], r2 = csr_sw[i2], r3 = csr_sw[i3];
    const float w0 = (e0 < end) ? __int_as_float(r0.y) : 0.0f;
    const float w1 = (e1 < end) ? __int_as_float(r1.y) : 0.0f;
    const float w2 = (e2 < end) ? __int_as_float(r2.y) : 0.0f;
    const float w3 = (e3 < end) ? __int_as_float(r3.y) : 0.0f;
    const uint4 u0 = *(const uint4*)(h_bf + (size_t)r0.x * CC + t * 8);
    const uint4 u1 = *(const uint4*)(h_bf + (size_t)r1.x * CC + t * 8);
    const uint4 u2 = *(const uint4*)(h_bf + (size_t)r2.x * CC + t * 8);
    const uint4 u3 = *(const uint4*)(h_bf + (size_t)r3.x * CC + t * 8);
    acc[0] = fmaf(bflo(u0.x), w0, acc[0]); acc[1] = fmaf(bfhi(u0.x), w0, acc[1]);
    acc[2] = fmaf(bflo(u0.y), w0, acc[2]); acc[3] = fmaf(bfhi(u0.y), w0, acc[3]);
    acc[4] = fmaf(bflo(u0.z), w0, acc[4]); acc[5] = fmaf(bfhi(u0.z), w0, acc[5]);
    acc[6] = fmaf(bflo(u0.w), w0, acc[6]); acc[7] = fmaf(bfhi(u0.w), w0, acc[7]);
    acc[0] = fmaf(bflo(u1.x), w1, acc[0]); acc[1] = fmaf(bfhi(u1.x), w1, acc[1]);
    acc[2] = fmaf(bflo(u1.y), w1, acc[2]); acc[3] = fmaf(bfhi(u1.y), w1, acc[3]);
    acc[4] = fmaf(bflo(u1.z), w1, acc[4]); acc[5] = fmaf(bfhi(u1.z), w1, acc[5]);
    acc[6] = fmaf(bflo(u1.w), w1, acc[6]); acc[7] = fmaf(bfhi(u1.w), w1, acc[7]);
    acc[0] = fmaf(bflo(u2.x), w2, acc[0]); acc[1] = fmaf(bfhi(u2.x), w2, acc[1]);
    acc[2] = fmaf(bflo(u2.y), w2, acc[2]); acc[3] = fmaf(bfhi(u2.y), w2, acc[3]);
    acc[4] = fmaf(bflo(u2.z), w2, acc[4]); acc[5] = fmaf(bfhi(u2.z), w2, acc[5]);
    acc[6] = fmaf(bflo(u2.w), w2, acc[6]); acc[7] = fmaf(bfhi(u2.w), w2, acc[7]);
    acc[0] = fmaf(bflo(u3.x), w3, acc[0]); acc[1] = fmaf(bfhi(u3.x), w3, acc[1]);
    acc[2] = fmaf(bflo(u3.y), w3, acc[2]); acc[3] = fmaf(bfhi(u3.y), w3, acc[3]);
    acc[4] = fmaf(bflo(u3.z), w3, acc[4]); acc[5] = fmaf(bfhi(u3.z), w3, acc[5]);
    acc[6] = fmaf(bflo(u3.w), w3, acc[6]); acc[7] = fmaf(bfhi(u3.w), w3, acc[7]);
  }

  #pragma unroll
  for (int i = 0; i < 8; ++i) {
    acc[i] += __shfl_xor(acc[i], 16, 64);
    acc[i] += __shfl_xor(acc[i], 32, 64);
  }

  if (q == 0) {
    uint4 o;
    o.x = (unsigned)f2bf(acc[0]) | ((unsigned)f2bf(acc[1]) << 16);
    o.y = (unsigned)f2bf(acc[2]) | ((unsigned)f2bf(acc[3]) << 16);
    o.z = (unsigned)f2bf(acc[4]) | ((unsigned)f2bf(acc[5]) << 16);
    o.w = (unsigned)f2bf(acc[6]) | ((unsigned)f2bf(acc[7]) << 16);
    *(uint4*)(agg_bf + (size_t)node * CC + t * 8) = o;
  }
}

// GRU via MFMA, in-place h. Wave snapshot of its 32 h-rows in LDS (padded):
// aH fragments + blend ho values come from LDS, killing the 64 dependent
// global 2B loads per thread in the epilogue.
__global__ __launch_bounds__(256) void gru_kernel(
    const unsigned short* __restrict__ agg_bf, unsigned short* __restrict__ h_bf,
    const unsigned short* __restrict__ Wfuse_p, const unsigned short* __restrict__ Whh_p,
    const float* __restrict__ b_ih, const float* __restrict__ b_hh)
{
  __shared__ unsigned short hbuf[4][32][136];   // 136 = 128 + 8 pad -> 272B row stride
  const int lane = threadIdx.x & 63;
  const int wave = threadIdx.x >> 6;
  const int node0 = blockIdx.x * 128 + wave * 32;
  if (node0 >= NN) return;
  const int col16 = lane & 15, grp = lane >> 4;

  // snapshot 32 rows (8KB) into LDS, vectorized + coalesced
  #pragma unroll
  for (int i = 0; i < 8; ++i) {
    const int chunk = lane + 64 * i;          // 0..511
    const int row = chunk >> 4, c16 = chunk & 15;
    uint4 v = *(const uint4*)(h_bf + (size_t)(node0 + row) * CC + c16 * 8);
    *(uint4*)&hbuf[wave][row][c16 * 8] = v;
  }

  bf16x8 aA[2][4], aH[2][4];
  #pragma unroll
  for (int t = 0; t < 2; ++t) {
    const unsigned short* arow = agg_bf + (size_t)(node0 + t * 16 + col16) * CC + grp * 8;
    #pragma unroll
    for (int ks = 0; ks < 4; ++ks) {
      aA[t][ks] = *(const bf16x8*)(arow + ks * 32);
      aH[t][ks] = *(const bf16x8*)&hbuf[wave][t * 16 + col16][grp * 8 + ks * 32];
    }
  }

  const f32x4 z4 = {0.f, 0.f, 0.f, 0.f};

  #pragma unroll
  for (int cb = 0; cb < 8; ++cb) {
    f32x4 air[2] = {z4, z4}, ahr[2] = {z4, z4};
    f32x4 aiz[2] = {z4, z4}, ahz[2] = {z4, z4};
    f32x4 ain[2] = {z4, z4}, ahn[2] = {z4, z4};
    #pragma unroll
    for (int ks = 0; ks < 4; ++ks) {
      const size_t or_ = (size_t)((cb * 4 + ks) * 64 + lane) * 8;
      const size_t oz_ = (size_t)(((8 + cb) * 4 + ks) * 64 + lane) * 8;
      const size_t on_ = (size_t)(((16 + cb) * 4 + ks) * 64 + lane) * 8;
      bf16x8 bir = *(const bf16x8*)(Wfuse_p + or_);
      bf16x8 bhr = *(const bf16x8*)(Whh_p + or_);
      bf16x8 biz = *(const bf16x8*)(Wfuse_p + oz_);
      bf16x8 bhz = *(const bf16x8*)(Whh_p + oz_);
      bf16x8 bin = *(const bf16x8*)(Wfuse_p + on_);
      bf16x8 bhn = *(const bf16x8*)(Whh_p + on_);
      #pragma unroll
      for (int t = 0; t < 2; ++t) {
        air[t] = __builtin_amdgcn_mfma_f32_16x16x32_bf16(aA[t][ks], bir, air[t], 0, 0, 0);
        ahr[t] = __builtin_amdgcn_mfma_f32_16x16x32_bf16(aH[t][ks], bhr, ahr[t], 0, 0, 0);
        aiz[t] = __builtin_amdgcn_mfma_f32_16x16x32_bf16(aA[t][ks], biz, aiz[t], 0, 0, 0);
        ahz[t] = __builtin_amdgcn_mfma_f32_16x16x32_bf16(aH[t][ks], bhz, ahz[t], 0, 0, 0);
        ain[t] = __builtin_amdgcn_mfma_f32_16x16x32_bf16(aA[t][ks], bin, ain[t], 0, 0, 0);
        ahn[t] = __builtin_amdgcn_mfma_f32_16x16x32_bf16(aH[t][ks], bhn, ahn[t], 0, 0, 0);
      }
    }
    const int o = cb * 16 + col16;
    const float bir_ = b_ih[o],       bhr_ = b_hh[o];
    const float biz_ = b_ih[128 + o], bhz_ = b_hh[128 + o];
    const float bin_ = b_ih[256 + o], bhn_ = b_hh[256 + o];
    #pragma unroll
    for (int t = 0; t < 2; ++t) {
      #pragma unroll
      for (int r = 0; r < 4; ++r) {
        float rr = sigmoidf_(air[t][r] + ahr[t][r] + bir_ + bhr_);
        float zz = sigmoidf_(aiz[t][r] + ahz[t][r] + biz_ + bhz_);
        float nn = tanhf_(ain[t][r] + bin_ + rr * (ahn[t][r] + bhn_));
        const int row = t * 16 + grp * 4 + r;
        float ho = bf2f(hbuf[wave][row][o]);          // LDS, not global
        h_bf[(size_t)(node0 + row) * CC + o] = f2bf((1.0f - zz) * nn + zz * ho);
      }
    }
  }
}

// out[batch[n]] += h[n] . W_prop + b_prop   (wave per node; bf16 h)
__global__ __launch_bounds__(256) void prop_kernel(
    const unsigned short* __restrict__ h_bf, const int* __restrict__ batch,
    const float* __restrict__ Wp, const float* __restrict__ bp,
    float* __restrict__ out)
{
  const int lane = threadIdx.x & 63;
  const int wid = (blockIdx.x * blockDim.x + threadIdx.x) >> 6;
  const int nw = (gridDim.x * blockDim.x) >> 6;
  for (int node = wid; node < NN; node += nw) {
    unsigned int u = *(const unsigned int*)(h_bf + (size_t)node * CC + 2 * lane);
    float v = bflo(u) * Wp[2 * lane] + bfhi(u) * Wp[2 * lane + 1];
    #pragma unroll
    for (int off = 32; off > 0; off >>= 1) v += __shfl_down(v, off, 64);
    if (lane == 0) atomicAdd(&out[batch[node]], v + bp[0]);
  }
}

extern "C" void kernel_launch(void* const* d_in, const int* in_sizes, int n_in,
                              void* d_out, int out_size, void* d_ws, size_t ws_size,
                              hipStream_t stream)
{
  const float* x      = (const float*)d_in[0];
  const int*   eidx   = (const int*)d_in[1];
  const float* ew     = (const float*)d_in[2];
  const int*   batch  = (const int*)d_in[3];
  const float* W_emb  = (const float*)d_in[4];
  const float* b_emb  = (const float*)d_in[5];
  const float* W      = (const float*)d_in[6];
  const float* W_ih   = (const float*)d_in[7];
  const float* W_hh   = (const float*)d_in[8];
  const float* b_ih   = (const float*)d_in[9];
  const float* b_hh   = (const float*)d_in[10];
  const float* W_prop = (const float*)d_in[11];
  const float* b_prop = (const float*)d_in[12];
  float* out = (float*)d_out;

  // workspace layout (~66 MB)
  char* p = (char*)d_ws;
  unsigned short* h_bf  = (unsigned short*)p; p += (size_t)NN * CC * sizeof(short);  // 25.6 MB
  unsigned short* agg   = (unsigned short*)p; p += (size_t)NN * CC * sizeof(short);  // 25.6 MB
  int2* csr_sw          = (int2*)p;           p += (size_t)EE * sizeof(int2);        // 12.8 MB
  unsigned short* Wfuse_p = (unsigned short*)p; p += (size_t)LL * 49152 * sizeof(short);
  unsigned short* Whh_p = (unsigned short*)p; p += (size_t)49152 * sizeof(short);
  int* deg     = (int*)p;                     p += (size_t)(NN + 256) * sizeof(int);
  int* row_ptr = (int*)p;                     p += (size_t)(NN + 256) * sizeof(int);
  int* cursor  = (int*)p;                     p += (size_t)(NN + 256) * sizeof(int);
  int* bsum    = (int*)p;                     p += 1024 * sizeof(int);

  const int NB_SCAN = (NN + 1023) / 1024;   // 98
  const int EB = (EE + 255) / 256;          // 6250
  const int MB2 = (NN + 127) / 128;         // 782

  // ---- fused prepack + zero-init (deg, out) ----
  pack_all_kernel<<<PK_TOTAL, 256, 0, stream>>>(W, W_ih, W_hh, Whh_p, Wfuse_p, deg, out);

  // ---- CSR build (direct scatter fill) ----
  hist_kernel<<<EB, 256, 0, stream>>>(eidx, deg);
  scan1_kernel<<<NB_SCAN, 256, 0, stream>>>(deg, bsum);
  scan2_kernel<<<1, 64, 0, stream>>>(bsum, NB_SCAN);
  scan3_kernel<<<NB_SCAN, 256, 0, stream>>>(deg, bsum, row_ptr, cursor);
  fill_kernel<<<EB, 256, 0, stream>>>(eidx, ew, cursor, csr_sw);

  // ---- main pipeline (in-place h) ----
  embed_kernel<<<NN, 128, 0, stream>>>(x, W_emb, b_emb, h_bf);

  for (int l = 0; l < LL; ++l) {
    aggregate_kernel<<<(NN + 3) / 4, 256, 0, stream>>>(h_bf, row_ptr, csr_sw, agg);
    gru_kernel<<<MB2, 256, 0, stream>>>(agg, h_bf,
                                        Wfuse_p + (size_t)l * 49152, Whh_p, b_ih, b_hh);
  }

  prop_kernel<<<2048, 256, 0, stream>>>(h_bf, batch, W_prop, b_prop, out);
}